// Round 2
// baseline (317.765 us; speedup 1.0000x reference)
//
#include <hip/hip_runtime.h>

// Problem constants
#define B_     16384
#define TD     512     // T*D
#define HID    128
#define LAT    512     // N_TOKENS*CODE_DIM
#define NCODES 512
#define CDIM   64
#define NTOK   8
#define EPS    1e-5f
#define MARGIN 0.02f   // ~10x worst-case approx-distance error (2.6e-3) post-LN

typedef unsigned short u16;
typedef unsigned int   u32;
typedef short bf16x8 __attribute__((ext_vector_type(8)));   // 8 bf16 = 4 VGPR (MFMA A/B frag)
typedef float f32x4  __attribute__((ext_vector_type(4)));   // MFMA C/D frag

__device__ __forceinline__ u16 bf16_rn(float f){
    u32 u = __float_as_uint(f);
    return (u16)((u + 0x7fffu + ((u >> 16) & 1u)) >> 16);   // round-nearest-even
}
__device__ __forceinline__ float bf16_f(u16 h){ return __uint_as_float(((u32)h) << 16); }
__device__ __forceinline__ void split2(float f, u16& hi, u16& lo){
    hi = bf16_rn(f);
    lo = bf16_rn(f - bf16_f(hi));     // residual: |a - hi - lo| <= ~2^-18 |a|
}
#define MFMA16(a,b,c) __builtin_amdgcn_mfma_f32_16x16x32_bf16((a),(b),(c),0,0,0)

// ---------------------------------------------------------------------------
// Prep: c2[c] = ||codebook[c]||^2 (fp32 exact)
// ---------------------------------------------------------------------------
__global__ void c2_kernel(const float* __restrict__ cb, float* __restrict__ c2) {
    int c = blockIdx.x;
    int d = threadIdx.x;            // 64 threads = 1 wave
    float v = cb[c * CDIM + d];
    float s = v * v;
#pragma unroll
    for (int m = 32; m >= 1; m >>= 1) s += __shfl_xor(s, m, 64);
    if (d == 0) c2[c] = s;
}

// ---------------------------------------------------------------------------
// Prep: transpose+split W[K][N] -> hi/lo planes [N][K] (bf16)
// ---------------------------------------------------------------------------
__global__ void tsplit_kernel(const float* __restrict__ W, u16* __restrict__ hi,
                              u16* __restrict__ lo, int N, int kshift){
    int id = blockIdx.x * 256 + threadIdx.x;    // over N*K output elems
    int K = 1 << kshift;
    int n = id >> kshift, k = id & (K - 1);
    u16 h, l2; split2(W[(size_t)k * N + n], h, l2);
    hi[id] = h; lo[id] = l2;
}
// Prep: split codebook [512][64] (no transpose)
__global__ void csplit_kernel(const float* __restrict__ C, u16* __restrict__ hi,
                              u16* __restrict__ lo){
    int id = blockIdx.x * 256 + threadIdx.x;
    u16 h, l2; split2(C[id], h, l2);
    hi[id] = h; lo[id] = l2;
}

// ---------------------------------------------------------------------------
// ENCODER PATH (must match fp32 reference numerics class): baseline VALU fp32
// tiled GEMM. C[M,N] = A[M,K] @ W[K,N] + bias, optional ReLU / LayerNorm
// (LN over groups of 64 output cols == one token).
// BM=64, BN=64, BK=32, 256 threads, 4x4 microtile. [proven-passing baseline]
// ---------------------------------------------------------------------------
template<bool RELU, bool LN>
__launch_bounds__(256)
__global__ void gemm_kernel(const float* __restrict__ A, const float* __restrict__ W,
                            const float* __restrict__ bias,
                            float* __restrict__ C,
                            int M, int N, int K) {
    constexpr int BM = 64, BN = 64, BK = 32;
    __shared__ float As[BK][BM + 4];   // transposed: As[k][m]
    __shared__ float Ws[BK][BN + 4];

    const int tid = threadIdx.x;
    const int tx  = tid & 15;          // 0..15 (cols)
    const int ty  = tid >> 4;          // 0..15 (rows)
    const int m0  = blockIdx.x * BM;
    const int n0  = blockIdx.y * BN;

    float acc[4][4] = {};

    for (int k0 = 0; k0 < K; k0 += BK) {
        {
            int r  = tid >> 3;               // 0..31
            int c4 = (tid & 7) * 4;          // 0..28
#pragma unroll
            for (int h = 0; h < 2; ++h) {
                int rr = r + h * 32;
                float4 v = *(const float4*)&A[(size_t)(m0 + rr) * K + k0 + c4];
                As[c4 + 0][rr] = v.x; As[c4 + 1][rr] = v.y;
                As[c4 + 2][rr] = v.z; As[c4 + 3][rr] = v.w;
            }
        }
        {
            int r  = tid >> 4;               // 0..15
            int c4 = (tid & 15) * 4;         // 0..60
#pragma unroll
            for (int h = 0; h < 2; ++h) {
                int rr = r + h * 16;
                float4 v = *(const float4*)&W[(size_t)(k0 + rr) * N + n0 + c4];
                *(float4*)&Ws[rr][c4] = v;
            }
        }
        __syncthreads();

#pragma unroll
        for (int kk = 0; kk < BK; ++kk) {
            float4 a = *(const float4*)&As[kk][ty * 4];
            float4 b = *(const float4*)&Ws[kk][tx * 4];
            float av[4] = {a.x, a.y, a.z, a.w};
            float bv[4] = {b.x, b.y, b.z, b.w};
#pragma unroll
            for (int i = 0; i < 4; ++i)
#pragma unroll
                for (int j = 0; j < 4; ++j)
                    acc[i][j] = fmaf(av[i], bv[j], acc[i][j]);
        }
        __syncthreads();
    }

    float bv[4];
#pragma unroll
    for (int j = 0; j < 4; ++j) bv[j] = bias[n0 + tx * 4 + j];

#pragma unroll
    for (int i = 0; i < 4; ++i) {
        float c[4];
#pragma unroll
        for (int j = 0; j < 4; ++j) {
            c[j] = acc[i][j] + bv[j];
            if (RELU) c[j] = fmaxf(c[j], 0.0f);
        }
        if (LN) {
            float s  = c[0] + c[1] + c[2] + c[3];
            float ss = c[0]*c[0] + c[1]*c[1] + c[2]*c[2] + c[3]*c[3];
#pragma unroll
            for (int m = 1; m <= 8; m <<= 1) {
                s  += __shfl_xor(s,  m, 64);
                ss += __shfl_xor(ss, m, 64);
            }
            float mean = s * (1.0f / 64.0f);
            float var  = ss * (1.0f / 64.0f) - mean * mean;
            float rstd = rsqrtf(var + EPS);
#pragma unroll
            for (int j = 0; j < 4; ++j) c[j] = (c[j] - mean) * rstd;
        }
        size_t row = (size_t)(m0 + ty * 4 + i);
        *(float4*)&C[row * N + n0 + tx * 4] = make_float4(c[0], c[1], c[2], c[3]);
    }
}

// ---------------------------------------------------------------------------
// DECODER PATH: split-bf16 MFMA GEMM (3-pass Markidis). Error ~1e-4 absolute,
// well inside recon threshold. A fp32 (split on the fly) or pre-split planes.
// B pre-split W^T planes [N][K]. Block 256 thr = 4 waves (2Mx2N), BN=128,
// BK=32. LDS 16B chunks [row][chunk], phys_ch = ch ^ ((row>>1)&3).
// ---------------------------------------------------------------------------
template<int BM, bool AFP32, bool RELU, bool SPLITOUT>
__launch_bounds__(256, 2)
__global__ void gemm_split(const float* __restrict__ Af,
                           const u16* __restrict__ Ahi, const u16* __restrict__ Alo,
                           const u16* __restrict__ Bhi, const u16* __restrict__ Blo,
                           const float* __restrict__ bias,
                           u16* __restrict__ Ohi, u16* __restrict__ Olo,
                           float* __restrict__ Of,
                           int M, int N, int K)
{
    constexpr int WM  = BM / 2;
    constexpr int MI  = WM / 16;
    constexpr int AIT = BM / 32;

    __shared__ uint4 As[2][BM * 4];
    __shared__ uint4 Bs[2][128 * 4];

    const int tid = threadIdx.x;
    const int wid = tid >> 6, l = tid & 63, ln = l & 15, kg = l >> 4;
    const int mw = wid >> 1, nw = wid & 1;
    const int m0 = blockIdx.x * BM, n0 = blockIdx.y * 128;
    const int swz = (ln >> 1) & 3;

    f32x4 acc[MI][4];
#pragma unroll
    for (int i = 0; i < MI; ++i)
#pragma unroll
        for (int j = 0; j < 4; ++j) acc[i][j] = (f32x4){0.f, 0.f, 0.f, 0.f};

    float4 rx0, rx1;
    uint4  ra[AIT > 0 ? AIT : 1];
    uint4  rb[4];

    const int axr = tid >> 2, axc = tid & 3;

    auto gload = [&](int k0){
        if constexpr (AFP32){
            const float* p = Af + (size_t)(m0 + axr) * K + k0 + axc * 8;
            rx0 = *(const float4*)p; rx1 = *(const float4*)(p + 4);
        } else {
#pragma unroll
            for (int h = 0; h < AIT; ++h){
                int idx = tid + 256 * h; int r = idx >> 3, pl = (idx >> 2) & 1, c = idx & 3;
                const u16* p = (pl ? Alo : Ahi) + (size_t)(m0 + r) * K + k0 + c * 8;
                ra[h] = *(const uint4*)p;
            }
        }
#pragma unroll
        for (int h = 0; h < 4; ++h){
            int idx = tid + 256 * h; int r = idx >> 3, pl = (idx >> 2) & 1, c = idx & 3;
            const u16* p = (pl ? Blo : Bhi) + (size_t)(n0 + r) * K + k0 + c * 8;
            rb[h] = *(const uint4*)p;
        }
    };
    auto lstore = [&](){
        if constexpr (AFP32){
            u16 hs[8] __attribute__((aligned(16)));
            u16 ls[8] __attribute__((aligned(16)));
            float v[8] = {rx0.x, rx0.y, rx0.z, rx0.w, rx1.x, rx1.y, rx1.z, rx1.w};
#pragma unroll
            for (int j = 0; j < 8; ++j) split2(v[j], hs[j], ls[j]);
            int pc = axc ^ ((axr >> 1) & 3);
            As[0][axr * 4 + pc] = *(const uint4*)hs;
            As[1][axr * 4 + pc] = *(const uint4*)ls;
        } else {
#pragma unroll
            for (int h = 0; h < AIT; ++h){
                int idx = tid + 256 * h; int r = idx >> 3, pl = (idx >> 2) & 1, c = idx & 3;
                As[pl][r * 4 + (c ^ ((r >> 1) & 3))] = ra[h];
            }
        }
#pragma unroll
        for (int h = 0; h < 4; ++h){
            int idx = tid + 256 * h; int r = idx >> 3, pl = (idx >> 2) & 1, c = idx & 3;
            Bs[pl][r * 4 + (c ^ ((r >> 1) & 3))] = rb[h];
        }
    };

    gload(0);
    for (int k0 = 0; k0 < K; k0 += 32){
        if (k0) __syncthreads();
        lstore();
        __syncthreads();
        if (k0 + 32 < K) gload(k0 + 32);

        bf16x8 af[MI][2], bf[4][2];
#pragma unroll
        for (int mi = 0; mi < MI; ++mi){
            int r = mw * WM + mi * 16 + ln;
            af[mi][0] = *(bf16x8*)&As[0][r * 4 + (kg ^ swz)];
            af[mi][1] = *(bf16x8*)&As[1][r * 4 + (kg ^ swz)];
        }
#pragma unroll
        for (int ni = 0; ni < 4; ++ni){
            int r = nw * 64 + ni * 16 + ln;
            bf[ni][0] = *(bf16x8*)&Bs[0][r * 4 + (kg ^ swz)];
            bf[ni][1] = *(bf16x8*)&Bs[1][r * 4 + (kg ^ swz)];
        }
#pragma unroll
        for (int mi = 0; mi < MI; ++mi)
#pragma unroll
            for (int ni = 0; ni < 4; ++ni){
                acc[mi][ni] = MFMA16(af[mi][0], bf[ni][0], acc[mi][ni]);  // hi*hi
                acc[mi][ni] = MFMA16(af[mi][0], bf[ni][1], acc[mi][ni]);  // hi*lo
                acc[mi][ni] = MFMA16(af[mi][1], bf[ni][0], acc[mi][ni]);  // lo*hi
            }
    }

    // Epilogue. C/D frag: col = lane&15, row = (lane>>4)*4 + reg
    float bv[4];
#pragma unroll
    for (int ni = 0; ni < 4; ++ni) bv[ni] = bias[n0 + nw * 64 + ni * 16 + ln];

#pragma unroll
    for (int mi = 0; mi < MI; ++mi){
#pragma unroll
        for (int r = 0; r < 4; ++r){
            float v[4];
#pragma unroll
            for (int ni = 0; ni < 4; ++ni){
                v[ni] = acc[mi][ni][r] + bv[ni];
                if constexpr (RELU) v[ni] = fmaxf(v[ni], 0.f);
            }
            size_t row = (size_t)(m0 + mw * WM + mi * 16 + kg * 4 + r);
#pragma unroll
            for (int ni = 0; ni < 4; ++ni){
                int col = n0 + nw * 64 + ni * 16 + ln;
                if constexpr (SPLITOUT){
                    u16 h, lo2; split2(v[ni], h, lo2);
                    Ohi[row * N + col] = h;  Olo[row * N + col] = lo2;
                } else {
                    Of[row * N + col] = v[ni];
                }
            }
        }
    }
}

// ---------------------------------------------------------------------------
// VQ via MFMA: block = 64 tokens, 4 waves. z fp32 in, split on the fly to LDS
// hi/lo planes; codebook staged in 4 chunks of 128 codes; wave w scores codes
// w*32..w*32+31 of each chunk (4m x 2n frags, 3-pass). dist = c2[c] - 2*cross.
// Per-lane best/2nd -> 16-lane butterfly -> cross-wave combine. If
// (2nd - best) < MARGIN: exact fp32 re-score of all 512 codes from fp32 z.
// ---------------------------------------------------------------------------
__launch_bounds__(256, 2)
__global__ void vq_kernel2(const float* __restrict__ zln,
                           const u16* __restrict__ Chi, const u16* __restrict__ Clo,
                           const float* __restrict__ cbf, const float* __restrict__ c2,
                           float* __restrict__ zq_o, float* __restrict__ idx_o)
{
    __shared__ uint4 Az[2][64 * 8];     // z tile planes, swizzle ch ^ (row&7)
    __shared__ uint4 Bz[2][128 * 8];    // codebook chunk planes
    __shared__ float c2s[512];
    __shared__ float cB1[4][64], cB2[4][64];
    __shared__ int   cI1[4][64];
    __shared__ int   fI[64];
    __shared__ float zf[64];
    __shared__ int   nflag;
    __shared__ int   flagR[64];
    __shared__ float wB[4];
    __shared__ int   wI[4];

    const int tid = threadIdx.x;
    const int wid = tid >> 6, l = tid & 63, ln = l & 15, kg = l >> 4;
    const int m0 = blockIdx.x * 64;

    // stage z tile: on-the-fly fp32 -> bf16 hi/lo split
#pragma unroll
    for (int h = 0; h < 4; ++h){
        int idx = tid + 256 * h;         // 1024 quarter-rows of 4 dims
        int r = idx >> 4, q = idx & 15;
        float4 v = *(const float4*)&zln[(size_t)(m0 + r) * CDIM + q * 4];
        u16 hs[4] __attribute__((aligned(8)));
        u16 ls[4] __attribute__((aligned(8)));
        split2(v.x, hs[0], ls[0]); split2(v.y, hs[1], ls[1]);
        split2(v.z, hs[2], ls[2]); split2(v.w, hs[3], ls[3]);
        int c = q >> 1, half = q & 1;
        int ch = c ^ (r & 7);
        ((uint2*)&Az[0][r * 8 + ch])[half] = *(const uint2*)hs;
        ((uint2*)&Az[1][r * 8 + ch])[half] = *(const uint2*)ls;
    }
    c2s[tid] = c2[tid]; c2s[tid + 256] = c2[tid + 256];
    if (tid == 0) nflag = 0;
    // stage codebook chunk 0
#pragma unroll
    for (int h = 0; h < 8; ++h){
        int idx = tid + 256 * h; int r = idx >> 4, pl = (idx >> 3) & 1, c = idx & 7;
        const u16* p = (pl ? Clo : Chi) + (size_t)r * CDIM + c * 8;
        Bz[pl][r * 8 + (c ^ (r & 7))] = *(const uint4*)p;
    }
    __syncthreads();

    // A fragments (held in registers for all chunks)
    bf16x8 a[4][2][2];                  // [mi][kslice][plane]
#pragma unroll
    for (int mi = 0; mi < 4; ++mi){
        int r = mi * 16 + ln;
#pragma unroll
        for (int ks = 0; ks < 2; ++ks){
            int c = ks * 4 + kg;
            a[mi][ks][0] = *(bf16x8*)&Az[0][r * 8 + (c ^ (r & 7))];
            a[mi][ks][1] = *(bf16x8*)&Az[1][r * 8 + (c ^ (r & 7))];
        }
    }

    float b1[4][4], b2[4][4]; int i1[4][4];
#pragma unroll
    for (int mi = 0; mi < 4; ++mi)
#pragma unroll
        for (int r = 0; r < 4; ++r){ b1[mi][r] = 3.4e38f; b2[mi][r] = 3.4e38f; i1[mi][r] = 0; }

    for (int cc = 0; cc < 4; ++cc){
        bf16x8 b[2][2][2];
#pragma unroll
        for (int ni = 0; ni < 2; ++ni){
            int r = wid * 32 + ni * 16 + ln;
#pragma unroll
            for (int ks = 0; ks < 2; ++ks){
                int c = ks * 4 + kg;
                b[ni][ks][0] = *(bf16x8*)&Bz[0][r * 8 + (c ^ (r & 7))];
                b[ni][ks][1] = *(bf16x8*)&Bz[1][r * 8 + (c ^ (r & 7))];
            }
        }
        f32x4 acc[4][2];
#pragma unroll
        for (int mi = 0; mi < 4; ++mi)
#pragma unroll
            for (int ni = 0; ni < 2; ++ni) acc[mi][ni] = (f32x4){0.f, 0.f, 0.f, 0.f};
#pragma unroll
        for (int mi = 0; mi < 4; ++mi)
#pragma unroll
            for (int ni = 0; ni < 2; ++ni)
#pragma unroll
                for (int ks = 0; ks < 2; ++ks){
                    acc[mi][ni] = MFMA16(a[mi][ks][0], b[ni][ks][0], acc[mi][ni]);
                    acc[mi][ni] = MFMA16(a[mi][ks][0], b[ni][ks][1], acc[mi][ni]);
                    acc[mi][ni] = MFMA16(a[mi][ks][1], b[ni][ks][0], acc[mi][ni]);
                }
#pragma unroll
        for (int mi = 0; mi < 4; ++mi)
#pragma unroll
            for (int ni = 0; ni < 2; ++ni){
                int code = cc * 128 + wid * 32 + ni * 16 + ln;
#pragma unroll
                for (int r = 0; r < 4; ++r){
                    float d = fmaf(-2.f, acc[mi][ni][r], c2s[code]);
                    if (d < b1[mi][r]) { b2[mi][r] = b1[mi][r]; b1[mi][r] = d; i1[mi][r] = code; }
                    else if (d < b2[mi][r]) b2[mi][r] = d;
                }
            }
        if (cc < 3){
            __syncthreads();
#pragma unroll
            for (int h = 0; h < 8; ++h){
                int idx = tid + 256 * h; int r = idx >> 4, pl = (idx >> 3) & 1, c = idx & 7;
                const u16* p = (pl ? Clo : Chi) + (size_t)((cc + 1) * 128 + r) * CDIM + c * 8;
                Bz[pl][r * 8 + (c ^ (r & 7))] = *(const uint4*)p;
            }
            __syncthreads();
        }
    }

    // butterfly over the 16 lanes holding a row's columns (tie -> lower idx)
#pragma unroll
    for (int mi = 0; mi < 4; ++mi)
#pragma unroll
        for (int r = 0; r < 4; ++r){
            float v1 = b1[mi][r], v2 = b2[mi][r]; int ii = i1[mi][r];
#pragma unroll
            for (int mk = 1; mk <= 8; mk <<= 1){
                float o1 = __shfl_xor(v1, mk, 64), o2 = __shfl_xor(v2, mk, 64);
                int   oi = __shfl_xor(ii, mk, 64);
                float n2 = fminf(fmaxf(v1, o1), fminf(v2, o2));   // 2nd-smallest of union
                if (o1 < v1 || (o1 == v1 && oi < ii)){ v1 = o1; ii = oi; }
                v2 = n2;
            }
            if (ln == 0){
                int row = mi * 16 + kg * 4 + r;
                cB1[wid][row] = v1; cB2[wid][row] = v2; cI1[wid][row] = ii;
            }
        }
    __syncthreads();
    if (tid < 64){
        float v1 = cB1[0][tid], v2 = cB2[0][tid]; int ii = cI1[0][tid];
#pragma unroll
        for (int w = 1; w < 4; ++w){
            float o1 = cB1[w][tid], o2 = cB2[w][tid]; int oi = cI1[w][tid];
            float n2 = fminf(fmaxf(v1, o1), fminf(v2, o2));
            if (o1 < v1 || (o1 == v1 && oi < ii)){ v1 = o1; ii = oi; }
            v2 = n2;
        }
        fI[tid] = ii;
        if (v2 - v1 < MARGIN){ int s = atomicAdd(&nflag, 1); flagR[s] = tid; }
    }
    __syncthreads();

    // exact fp32 rescue for ambiguous tokens (reads true fp32 z)
    int nf = nflag;
    for (int f = 0; f < nf; ++f){
        int row = flagR[f];
        if (tid < 64) zf[tid] = zln[(size_t)(m0 + row) * CDIM + tid];
        __syncthreads();
        float bb = 3.4e38f; int bi = 0;
#pragma unroll
        for (int cH = 0; cH < 2; ++cH){
            int cc = tid + 256 * cH;
            const float* cp = cbf + (size_t)cc * CDIM;
            float dot = 0.f;
#pragma unroll
            for (int dd = 0; dd < 64; ++dd) dot = fmaf(zf[dd], cp[dd], dot);
            float d = fmaf(-2.f, dot, c2s[cc]);
            if (d < bb){ bb = d; bi = cc; }     // cc strictly ascending per thread
        }
#pragma unroll
        for (int mk = 1; mk < 64; mk <<= 1){
            float o = __shfl_xor(bb, mk, 64); int oi = __shfl_xor(bi, mk, 64);
            if (o < bb || (o == bb && oi < bi)){ bb = o; bi = oi; }
        }
        if (l == 0){ wB[wid] = bb; wI[wid] = bi; }
        __syncthreads();
        if (tid == 0){
            float v1 = wB[0]; int ii = wI[0];
#pragma unroll
            for (int w = 1; w < 4; ++w)
                if (wB[w] < v1 || (wB[w] == v1 && wI[w] < ii)){ v1 = wB[w]; ii = wI[w]; }
            fI[row] = ii;
        }
        __syncthreads();
    }

    // gather + outputs: 4 threads per row, 16 dims each (fp32, exact)
    {
        int row = tid >> 2, part = tid & 3;
        int ii  = fI[row];
        size_t gr = (size_t)(m0 + row);
        const float* cf = cbf + (size_t)ii * CDIM + part * 16;
        float4 q0 = *(const float4*)(cf + 0),  q1 = *(const float4*)(cf + 4);
        float4 q2 = *(const float4*)(cf + 8),  q3 = *(const float4*)(cf + 12);
        float* zo = zq_o + gr * CDIM + part * 16;
        *(float4*)(zo + 0) = q0; *(float4*)(zo + 4)  = q1;
        *(float4*)(zo + 8) = q2; *(float4*)(zo + 12) = q3;
        if (part == 0) idx_o[gr] = (float)ii;
    }
}

// ---------------------------------------------------------------------------
extern "C" void kernel_launch(void* const* d_in, const int* in_sizes, int n_in,
                              void* d_out, int out_size, void* d_ws, size_t ws_size,
                              hipStream_t stream) {
    const float* x      = (const float*)d_in[0];
    const float* enc_w1 = (const float*)d_in[1];
    const float* enc_b1 = (const float*)d_in[2];
    const float* enc_w2 = (const float*)d_in[3];
    const float* enc_b2 = (const float*)d_in[4];
    const float* cbk    = (const float*)d_in[5];
    const float* dec_w1 = (const float*)d_in[6];
    const float* dec_b1 = (const float*)d_in[7];
    const float* dec_w2 = (const float*)d_in[8];
    const float* dec_b2 = (const float*)d_in[9];

    // outputs, all float32, concatenated flat: recon | z_q | indices
    float* out     = (float*)d_out;
    float* recon_o = out;
    float* zq_o    = out + (size_t)B_ * TD;
    float* idx_o   = out + 2 * (size_t)B_ * TD;

    // workspace carve-up
    float* zbuf  = (float*)d_ws;                       // [B,512] fp32 z (post-LN)
    float* hbuf  = zbuf + (size_t)B_ * TD;             // [B,128] fp32 enc hidden
    float* c2buf = hbuf + (size_t)B_ * HID;            // 512 fp32
    u16* w = (u16*)(c2buf + 512);
    u16* d1t_h = w; w += 65536;   u16* d1t_l = w; w += 65536;   // dec_w1^T [128][512]
    u16* d2t_h = w; w += 65536;   u16* d2t_l = w; w += 65536;   // dec_w2^T [512][128]
    u16* cb_h  = w; w += 32768;   u16* cb_l  = w; w += 32768;   // codebook [512][64]
    // decoder hidden planes alias hbuf (dead after encoder GEMM2)
    u16* h_h = (u16*)hbuf;
    u16* h_l = h_h + (size_t)B_ * HID;

    // ---- prep ----
    hipLaunchKernelGGL(tsplit_kernel, dim3(256), dim3(256), 0, stream, dec_w1, d1t_h, d1t_l, HID, 9);
    hipLaunchKernelGGL(tsplit_kernel, dim3(256), dim3(256), 0, stream, dec_w2, d2t_h, d2t_l, TD,  7);
    hipLaunchKernelGGL(csplit_kernel, dim3(128), dim3(256), 0, stream, cbk, cb_h, cb_l);
    hipLaunchKernelGGL(c2_kernel, dim3(NCODES), dim3(64), 0, stream, cbk, c2buf);

    // ---- encoder GEMM1 + ReLU (fp32 VALU): x[16384,512] @ w1 -> hbuf ----
    hipLaunchKernelGGL((gemm_kernel<true, false>), dim3(B_ / 64, HID / 64), dim3(256), 0,
                       stream, x, enc_w1, enc_b1, hbuf, B_, HID, TD);

    // ---- encoder GEMM2 + LN (fp32 VALU): hbuf @ w2 -> zbuf ----
    hipLaunchKernelGGL((gemm_kernel<false, true>), dim3(B_ / 64, LAT / 64), dim3(256), 0,
                       stream, hbuf, enc_w2, enc_b2, zbuf, B_, LAT, HID);

    // ---- VQ (MFMA + exact-fp32 margin rescue): writes zq_o fp32 + idx ----
    hipLaunchKernelGGL(vq_kernel2, dim3(B_ * NTOK / 64), dim3(256), 0, stream,
                       zbuf, cb_h, cb_l, cbk, c2buf, zq_o, idx_o);

    // ---- decoder GEMM1 + ReLU (MFMA, A = zq_o fp32 split on the fly) ----
    hipLaunchKernelGGL((gemm_split<64, true, true, true>), dim3(B_ / 64, 1), dim3(256), 0,
                       stream, zq_o, (const u16*)nullptr, (const u16*)nullptr,
                       d1t_h, d1t_l, dec_b1, h_h, h_l, (float*)nullptr, B_, HID, LAT);

    // ---- decoder GEMM2 (MFMA): h planes @ dw2 -> recon fp32 ----
    hipLaunchKernelGGL((gemm_split<128, false, false, false>), dim3(B_ / 128, TD / 128), dim3(256), 0,
                       stream, (const float*)nullptr, h_h, h_l,
                       d2t_h, d2t_l, dec_b2, (u16*)nullptr, (u16*)nullptr, recon_o, B_, TD, HID);
}